// Round 1
// baseline (705.294 us; speedup 1.0000x reference)
//
#include <hip/hip_runtime.h>
#include <stdint.h>

#define HW      16384
#define W_      128
#define NA      9
#define BS      8
#define K_TOP   100
#define NDET    800
#define C_FEAT  256
#define FC1_IN  2304
#define FC1_OUT 1024

// output offsets (floats)
#define O_HM    0
#define O_WH1   1179648
#define O_OFF1  1182848
#define O_S1CLS 1184448
#define O_WH2   1185248
#define O_OFF2  1188448
#define O_CLS   1190048
#define O_SWH   1198048
#define O_INDS  1201248
#define O_VAL   1202048

#define NBIN     4096
#define CAND_MAX 2048

// ---------------- top-k per batch ----------------
__global__ __launch_bounds__(1024) void topk_kernel(const float* __restrict__ hm,
                                                    float* __restrict__ out,
                                                    int* __restrict__ ws_inds) {
    const int b   = blockIdx.x;
    const int tid = threadIdx.x;
    __shared__ unsigned int hist[NBIN];
    __shared__ unsigned long long cand[CAND_MAX];
    __shared__ int s_T;
    __shared__ unsigned int s_cnt;

    for (int i = tid; i < NBIN; i += 1024) hist[i] = 0u;
    if (tid == 0) s_cnt = 0u;
    __syncthreads();

    const float* hmb = hm + (size_t)b * NA * HW;
    // pass 1: histogram (memory-order scan: idx = a*HW + p, coalesced)
    for (int idx = tid; idx < NA * HW; idx += 1024) {
        float v  = hmb[idx];
        int bin  = (int)(v * (float)NBIN);
        bin      = max(0, min(NBIN - 1, bin));
        atomicAdd(&hist[bin], 1u);
    }
    __syncthreads();
    if (tid == 0) {
        unsigned int acc = 0; int T = 0;
        for (int bin = NBIN - 1; bin >= 0; --bin) {
            acc += hist[bin];
            if (acc >= K_TOP) { T = bin; break; }
        }
        s_T = T;
    }
    __syncthreads();
    const int T = s_T;
    // pass 2: collect candidates
    for (int idx = tid; idx < NA * HW; idx += 1024) {
        float v = hmb[idx];
        int bin = (int)(v * (float)NBIN);
        bin     = max(0, min(NBIN - 1, bin));
        if (bin >= T) {
            unsigned int p = atomicAdd(&s_cnt, 1u);
            if (p < CAND_MAX) {
                int a = idx / HW;
                int pp = idx - a * HW;
                unsigned int flat_i = (unsigned int)(pp * NA + a);
                cand[p] = ((unsigned long long)__float_as_uint(v) << 32)
                        | (unsigned long long)(0xFFFFFFFFu - flat_i);
            }
        }
    }
    __syncthreads();
    unsigned int cnt = s_cnt; if (cnt > CAND_MAX) cnt = CAND_MAX;
    for (int i = tid; i < CAND_MAX; i += 1024)
        if (i >= (int)cnt) cand[i] = 0ull;
    __syncthreads();
    // bitonic sort, descending
    for (int k = 2; k <= CAND_MAX; k <<= 1) {
        for (int j = k >> 1; j > 0; j >>= 1) {
            for (int i = tid; i < CAND_MAX; i += 1024) {
                int ixj = i ^ j;
                if (ixj > i) {
                    unsigned long long a = cand[i], bb = cand[ixj];
                    bool up = ((i & k) == 0);
                    if (up ? (a < bb) : (a > bb)) { cand[i] = bb; cand[ixj] = a; }
                }
            }
            __syncthreads();
        }
    }
    if (tid < K_TOP) {
        unsigned long long key = cand[tid];
        float v = __uint_as_float((unsigned int)(key >> 32));
        unsigned int flat_i = 0xFFFFFFFFu - (unsigned int)(key & 0xFFFFFFFFull);
        int a = (int)(flat_i % NA);
        int p = (int)(flat_i / NA);
        int inds = p + b * HW;
        int o = b * K_TOP + tid;
        out[O_VAL + o]   = v;
        out[O_S1CLS + o] = (float)a;
        out[O_INDS + o]  = (float)inds;
        ws_inds[o] = inds;
    }
}

// ---------------- gather wh/offset, build boxes ----------------
__global__ void gather_kernel(const float* __restrict__ wh,
                              const float* __restrict__ offset,
                              const int* __restrict__ ws_inds,
                              float* __restrict__ out,
                              float* __restrict__ ws_boxes) {
    int n = blockIdx.x * blockDim.x + threadIdx.x;
    if (n >= NDET) return;
    int inds = ws_inds[n];
    // reference quirk: select_tensor indexes (b,hw,9) flat rows with inds<8*hw,
    // so the batch term is always 0 and p'=inds/9, a'=inds%9.
    int p = inds / NA;
    int a = inds - p * NA;
    float w0 = wh[(size_t)(a * 4 + 0) * HW + p];
    float w1 = wh[(size_t)(a * 4 + 1) * HW + p];
    float w2 = wh[(size_t)(a * 4 + 2) * HW + p];
    float w3 = wh[(size_t)(a * 4 + 3) * HW + p];
    float o0 = offset[(size_t)(a * 2 + 0) * HW + p];
    float o1 = offset[(size_t)(a * 2 + 1) * HW + p];
    out[O_WH1 + n * 4 + 0] = w0; out[O_WH1 + n * 4 + 1] = w1;
    out[O_WH1 + n * 4 + 2] = w2; out[O_WH1 + n * 4 + 3] = w3;
    out[O_WH2 + n * 4 + 0] = w0; out[O_WH2 + n * 4 + 1] = w1;
    out[O_WH2 + n * 4 + 2] = w2; out[O_WH2 + n * 4 + 3] = w3;
    out[O_OFF1 + n * 2 + 0] = o0; out[O_OFF1 + n * 2 + 1] = o1;
    out[O_OFF2 + n * 2 + 0] = o0; out[O_OFF2 + n * 2 + 1] = o1;
    float xs = (float)(inds % W_) + o0;   // == pos % 128
    float ys = (float)(inds / W_) + o1;   // includes b*128 (reference quirk)
    ws_boxes[n * 4 + 0] = xs + w0;
    ws_boxes[n * 4 + 1] = ys + w1;
    ws_boxes[n * 4 + 2] = xs + w2;
    ws_boxes[n * 4 + 3] = ys + w3;
}

// ---------------- roi align 3x3, write (n, c*9+gy*3+gx) ----------------
__global__ __launch_bounds__(256) void roi_kernel(const float* __restrict__ feat,
                                                  const float* __restrict__ ws_boxes,
                                                  float* __restrict__ ws_roi) {
    int n = blockIdx.x;
    int c = threadIdx.x;
    float x1 = ws_boxes[n * 4 + 0], y1 = ws_boxes[n * 4 + 1];
    float x2 = ws_boxes[n * 4 + 2], y2 = ws_boxes[n * 4 + 3];
    int b = n / K_TOP;
    float roi_w = fmaxf(x2 - x1, 1.0f);
    float roi_h = fmaxf(y2 - y1, 1.0f);
    float bw = roi_w / 3.0f;
    float bh = roi_h / 3.0f;
    const float* fb = feat + ((size_t)b * C_FEAT + c) * HW;
    float* op = ws_roi + (size_t)n * FC1_IN + (size_t)c * 9;
    #pragma unroll
    for (int gy = 0; gy < 3; ++gy) {
        float ysf = y1 + ((float)gy + 0.5f) * bh;
        #pragma unroll
        for (int gx = 0; gx < 3; ++gx) {
            float xsf = x1 + ((float)gx + 0.5f) * bw;
            bool invalid = (ysf < -1.0f) || (ysf > 128.0f) || (xsf < -1.0f) || (xsf > 128.0f);
            float y = fminf(fmaxf(ysf, 0.0f), 127.0f);
            float x = fminf(fmaxf(xsf, 0.0f), 127.0f);
            int y0 = (int)floorf(y);
            int x0 = (int)floorf(x);
            int y1i = min(y0 + 1, 127);
            int x1i = min(x0 + 1, 127);
            float ly = y - (float)y0, lx = x - (float)x0;
            float hy = 1.0f - ly, hx = 1.0f - lx;
            float v00 = fb[y0 * W_ + x0],  v01 = fb[y0 * W_ + x1i];
            float v10 = fb[y1i * W_ + x0], v11 = fb[y1i * W_ + x1i];
            float v = hy * hx * v00 + hy * lx * v01 + ly * hx * v10 + ly * lx * v11;
            op[gy * 3 + gx] = invalid ? 0.0f : v;
        }
    }
}

// ---------------- FC1: (800x2304)@(2304x1024)+b, relu ----------------
#define BM 64
#define BN 64
#define BKK 32
__global__ __launch_bounds__(256) void fc1_kernel(const float* __restrict__ A,
                                                  const float* __restrict__ B,
                                                  const float* __restrict__ bias,
                                                  float* __restrict__ C) {
    __shared__ float As[BM][BKK + 1];
    __shared__ float Bs[BKK][BN];
    int bm0 = blockIdx.x * BM;
    int bn0 = blockIdx.y * BN;
    int tid = threadIdx.x;
    int tx = tid & 15, ty = tid >> 4;
    float acc[4][4] = {{0.f}};
    for (int k0 = 0; k0 < FC1_IN; k0 += BKK) {
        for (int l = tid; l < BM * BKK; l += 256) {
            int r = l / BKK, kk = l % BKK;
            int gr = bm0 + r;
            As[r][kk] = (gr < NDET) ? A[(size_t)gr * FC1_IN + k0 + kk] : 0.0f;
        }
        for (int l = tid; l < BKK * BN; l += 256) {
            int kk = l / BN, cj = l % BN;
            Bs[kk][cj] = B[(size_t)(k0 + kk) * FC1_OUT + bn0 + cj];
        }
        __syncthreads();
        #pragma unroll
        for (int kk = 0; kk < BKK; ++kk) {
            float av[4], bv[4];
            #pragma unroll
            for (int i = 0; i < 4; ++i) av[i] = As[ty * 4 + i][kk];
            #pragma unroll
            for (int j = 0; j < 4; ++j) bv[j] = Bs[kk][tx * 4 + j];
            #pragma unroll
            for (int i = 0; i < 4; ++i)
                #pragma unroll
                for (int j = 0; j < 4; ++j) acc[i][j] += av[i] * bv[j];
        }
        __syncthreads();
    }
    #pragma unroll
    for (int i = 0; i < 4; ++i) {
        int gm = bm0 + ty * 4 + i;
        if (gm < NDET) {
            #pragma unroll
            for (int j = 0; j < 4; ++j) {
                int gn = bn0 + tx * 4 + j;
                C[(size_t)gm * FC1_OUT + gn] = fmaxf(acc[i][j] + bias[gn], 0.0f);
            }
        }
    }
}

// ---------------- FC2: heads ----------------
__global__ __launch_bounds__(256) void fc2_kernel(const float* __restrict__ hdn,
                                                  const float* __restrict__ w_cls,
                                                  const float* __restrict__ b_cls,
                                                  const float* __restrict__ w_wh,
                                                  const float* __restrict__ b_wh,
                                                  float* __restrict__ out) {
    int n = blockIdx.x;
    int tid = threadIdx.x;
    int lane = tid & 63, wv = tid >> 6;
    const float* h = hdn + (size_t)n * FC1_OUT;
    for (int j = wv; j < 14; j += 4) {
        float s = 0.0f;
        if (j < 10) {
            for (int k2 = lane; k2 < FC1_OUT; k2 += 64) s += h[k2] * w_cls[k2 * 10 + j];
        } else {
            int jj = j - 10;
            for (int k2 = lane; k2 < FC1_OUT; k2 += 64) s += h[k2] * w_wh[k2 * 4 + jj];
        }
        #pragma unroll
        for (int off = 32; off > 0; off >>= 1) s += __shfl_down(s, off);
        if (lane == 0) {
            if (j < 10) out[O_CLS + n * 10 + j] = s + b_cls[j];
            else        out[O_SWH + n * 4 + (j - 10)] = s + b_wh[j - 10];
        }
    }
}

extern "C" void kernel_launch(void* const* d_in, const int* in_sizes, int n_in,
                              void* d_out, int out_size, void* d_ws, size_t ws_size,
                              hipStream_t stream) {
    const float* feat   = (const float*)d_in[0];
    const float* hm     = (const float*)d_in[1];
    const float* wh     = (const float*)d_in[2];
    const float* offset = (const float*)d_in[3];
    const float* w_fc1  = (const float*)d_in[4];
    const float* b_fc1  = (const float*)d_in[5];
    const float* w_cls  = (const float*)d_in[6];
    const float* b_cls  = (const float*)d_in[7];
    const float* w_wh   = (const float*)d_in[8];
    const float* b_wh   = (const float*)d_in[9];
    float* out = (float*)d_out;

    char* ws = (char*)d_ws;
    int*   ws_inds  = (int*)ws;                                   // 800 ints
    float* ws_boxes = (float*)(ws + 4096);                        // 3200 f
    float* ws_roi   = (float*)(ws + 32768);                       // 800*2304 f
    float* ws_hdn   = (float*)(ws + 32768 + (size_t)NDET * FC1_IN * 4); // 800*1024 f

    // output 0: hm passthrough
    hipMemcpyAsync(out + O_HM, hm, (size_t)BS * NA * HW * sizeof(float),
                   hipMemcpyDeviceToDevice, stream);

    topk_kernel<<<BS, 1024, 0, stream>>>(hm, out, ws_inds);
    gather_kernel<<<(NDET + 255) / 256, 256, 0, stream>>>(wh, offset, ws_inds, out, ws_boxes);
    roi_kernel<<<NDET, 256, 0, stream>>>(feat, ws_boxes, ws_roi);
    dim3 g1((NDET + BM - 1) / BM, FC1_OUT / BN);
    fc1_kernel<<<g1, 256, 0, stream>>>(ws_roi, w_fc1, b_fc1, ws_hdn);
    fc2_kernel<<<NDET, 256, 0, stream>>>(ws_hdn, w_cls, b_cls, w_wh, b_wh, out);
}

// Round 2
// 313.550 us; speedup vs baseline: 2.2494x; 2.2494x over previous
//
#include <hip/hip_runtime.h>
#include <hip/hip_bf16.h>
#include <stdint.h>

#define HW      16384
#define W_      128
#define NA      9
#define BS      8
#define K_TOP   100
#define NDET    800
#define MPAD    832
#define C_FEAT  256
#define FC1_IN  2304
#define FC1_OUT 1024

// output offsets (floats)
#define O_HM    0
#define O_WH1   1179648
#define O_OFF1  1182848
#define O_S1CLS 1184448
#define O_WH2   1185248
#define O_OFF2  1188448
#define O_CLS   1190048
#define O_SWH   1198048
#define O_INDS  1201248
#define O_VAL   1202048

#define NBIN     4096
#define CAND_MAX 512

typedef __attribute__((ext_vector_type(8))) short short8v;
typedef __attribute__((ext_vector_type(4))) float f32x4;

__device__ __forceinline__ void gload16(const void* g, void* l) {
    __builtin_amdgcn_global_load_lds(
        (const __attribute__((address_space(1))) unsigned int*)g,
        (__attribute__((address_space(3))) unsigned int*)l, 16, 0, 0);
}

// ---------------- top-k per batch ----------------
__global__ __launch_bounds__(1024) void topk_kernel(const float* __restrict__ hm,
                                                    float* __restrict__ out,
                                                    int* __restrict__ ws_inds) {
    const int b   = blockIdx.x;
    const int tid = threadIdx.x;
    __shared__ unsigned int hist[NBIN];
    __shared__ unsigned long long cand[CAND_MAX];
    __shared__ int s_T;
    __shared__ unsigned int s_cnt;

    for (int i = tid; i < NBIN; i += 1024) hist[i] = 0u;
    if (tid == 0) s_cnt = 0u;
    __syncthreads();

    const float4* hm4 = (const float4*)(hm + (size_t)b * NA * HW);
    // pass 1: histogram, float4 loads
    for (int i = tid; i < (NA * HW) / 4; i += 1024) {
        float4 v = hm4[i];
        int b0 = max(0, min(NBIN - 1, (int)(v.x * (float)NBIN)));
        int b1 = max(0, min(NBIN - 1, (int)(v.y * (float)NBIN)));
        int b2 = max(0, min(NBIN - 1, (int)(v.z * (float)NBIN)));
        int b3 = max(0, min(NBIN - 1, (int)(v.w * (float)NBIN)));
        atomicAdd(&hist[b0], 1u); atomicAdd(&hist[b1], 1u);
        atomicAdd(&hist[b2], 1u); atomicAdd(&hist[b3], 1u);
    }
    __syncthreads();
    if (tid == 0) {
        unsigned int acc = 0; int T = 0;
        for (int bin = NBIN - 1; bin >= 0; --bin) {
            acc += hist[bin];
            if (acc >= K_TOP) { T = bin; break; }
        }
        s_T = T;
    }
    __syncthreads();
    const int T = s_T;
    // pass 2: collect candidates
    for (int i = tid; i < (NA * HW) / 4; i += 1024) {
        float4 v4 = hm4[i];
        float vv[4] = {v4.x, v4.y, v4.z, v4.w};
        #pragma unroll
        for (int e = 0; e < 4; ++e) {
            float v = vv[e];
            int bin = max(0, min(NBIN - 1, (int)(v * (float)NBIN)));
            if (bin >= T) {
                unsigned int p = atomicAdd(&s_cnt, 1u);
                if (p < CAND_MAX) {
                    int idx = i * 4 + e;
                    int a  = idx >> 14;          // / HW
                    int pp = idx & (HW - 1);
                    unsigned int flat_i = (unsigned int)(pp * NA + a);
                    cand[p] = ((unsigned long long)__float_as_uint(v) << 32)
                            | (unsigned long long)(0xFFFFFFFFu - flat_i);
                }
            }
        }
    }
    __syncthreads();
    unsigned int cnt = s_cnt; if (cnt > CAND_MAX) cnt = CAND_MAX;
    if (tid < CAND_MAX && tid >= (int)cnt) cand[tid] = 0ull;
    __syncthreads();
    // bitonic sort, descending (512 slots, one per thread for tid<512)
    for (int k = 2; k <= CAND_MAX; k <<= 1) {
        for (int j = k >> 1; j > 0; j >>= 1) {
            if (tid < CAND_MAX) {
                int i = tid;
                int ixj = i ^ j;
                if (ixj > i) {
                    unsigned long long a = cand[i], bb = cand[ixj];
                    bool up = ((i & k) == 0);
                    if (up ? (a < bb) : (a > bb)) { cand[i] = bb; cand[ixj] = a; }
                }
            }
            __syncthreads();
        }
    }
    if (tid < K_TOP) {
        unsigned long long key = cand[tid];
        float v = __uint_as_float((unsigned int)(key >> 32));
        unsigned int flat_i = 0xFFFFFFFFu - (unsigned int)(key & 0xFFFFFFFFull);
        int a = (int)(flat_i % NA);
        int p = (int)(flat_i / NA);
        int inds = p + b * HW;
        int o = b * K_TOP + tid;
        out[O_VAL + o]   = v;
        out[O_S1CLS + o] = (float)a;
        out[O_INDS + o]  = (float)inds;
        ws_inds[o] = inds;
    }
}

// ---------------- gather wh/offset, build boxes ----------------
__global__ void gather_kernel(const float* __restrict__ wh,
                              const float* __restrict__ offset,
                              const int* __restrict__ ws_inds,
                              float* __restrict__ out,
                              float* __restrict__ ws_boxes) {
    int n = blockIdx.x * blockDim.x + threadIdx.x;
    if (n >= NDET) return;
    int inds = ws_inds[n];
    // reference quirk: select_tensor row index omits the anchor term, so the
    // batch contribution vanishes and p'=inds/9, a'=inds%9 (always batch 0).
    int p = inds / NA;
    int a = inds - p * NA;
    float w0 = wh[(size_t)(a * 4 + 0) * HW + p];
    float w1 = wh[(size_t)(a * 4 + 1) * HW + p];
    float w2 = wh[(size_t)(a * 4 + 2) * HW + p];
    float w3 = wh[(size_t)(a * 4 + 3) * HW + p];
    float o0 = offset[(size_t)(a * 2 + 0) * HW + p];
    float o1 = offset[(size_t)(a * 2 + 1) * HW + p];
    out[O_WH1 + n * 4 + 0] = w0; out[O_WH1 + n * 4 + 1] = w1;
    out[O_WH1 + n * 4 + 2] = w2; out[O_WH1 + n * 4 + 3] = w3;
    out[O_WH2 + n * 4 + 0] = w0; out[O_WH2 + n * 4 + 1] = w1;
    out[O_WH2 + n * 4 + 2] = w2; out[O_WH2 + n * 4 + 3] = w3;
    out[O_OFF1 + n * 2 + 0] = o0; out[O_OFF1 + n * 2 + 1] = o1;
    out[O_OFF2 + n * 2 + 0] = o0; out[O_OFF2 + n * 2 + 1] = o1;
    float xs = (float)(inds % W_) + o0;   // == pos % 128
    float ys = (float)(inds / W_) + o1;   // includes b*128 (reference quirk)
    ws_boxes[n * 4 + 0] = xs + w0;
    ws_boxes[n * 4 + 1] = ys + w1;
    ws_boxes[n * 4 + 2] = xs + w2;
    ws_boxes[n * 4 + 3] = ys + w3;
}

// ---------------- roi align 3x3 -> bf16 A matrix [MPAD][2304] ----------------
__global__ __launch_bounds__(256) void roi_kernel(const float* __restrict__ feat,
                                                  const float* __restrict__ ws_boxes,
                                                  __hip_bfloat16* __restrict__ ws_roi) {
    int n = blockIdx.x;
    int c = threadIdx.x;
    __hip_bfloat16* op = ws_roi + (size_t)n * FC1_IN + (size_t)c * 9;
    if (n >= NDET) {   // zero-pad rows 800..831 for the MFMA tiles
        #pragma unroll
        for (int i = 0; i < 9; ++i) op[i] = __float2bfloat16(0.0f);
        return;
    }
    float x1 = ws_boxes[n * 4 + 0], y1 = ws_boxes[n * 4 + 1];
    float x2 = ws_boxes[n * 4 + 2], y2 = ws_boxes[n * 4 + 3];
    int b = n / K_TOP;
    float roi_w = fmaxf(x2 - x1, 1.0f);
    float roi_h = fmaxf(y2 - y1, 1.0f);
    float bw = roi_w / 3.0f;
    float bh = roi_h / 3.0f;
    const float* fb = feat + ((size_t)b * C_FEAT + c) * HW;
    #pragma unroll
    for (int gy = 0; gy < 3; ++gy) {
        float ysf = y1 + ((float)gy + 0.5f) * bh;
        #pragma unroll
        for (int gx = 0; gx < 3; ++gx) {
            float xsf = x1 + ((float)gx + 0.5f) * bw;
            bool invalid = (ysf < -1.0f) || (ysf > 128.0f) || (xsf < -1.0f) || (xsf > 128.0f);
            float y = fminf(fmaxf(ysf, 0.0f), 127.0f);
            float x = fminf(fmaxf(xsf, 0.0f), 127.0f);
            int y0 = (int)floorf(y);
            int x0 = (int)floorf(x);
            int y1i = min(y0 + 1, 127);
            int x1i = min(x0 + 1, 127);
            float ly = y - (float)y0, lx = x - (float)x0;
            float hy = 1.0f - ly, hx = 1.0f - lx;
            float v00 = fb[y0 * W_ + x0],  v01 = fb[y0 * W_ + x1i];
            float v10 = fb[y1i * W_ + x0], v11 = fb[y1i * W_ + x1i];
            float v = hy * hx * v00 + hy * lx * v01 + ly * hx * v10 + ly * lx * v11;
            op[gy * 3 + gx] = __float2bfloat16(invalid ? 0.0f : v);
        }
    }
}

// ---------------- W transpose+convert: [2304][1024] f32 -> [1024][2304] bf16 ----
__global__ __launch_bounds__(256) void wt_kernel(const float* __restrict__ w,
                                                 __hip_bfloat16* __restrict__ wt) {
    __shared__ float t[64][65];
    int bk = blockIdx.x * 64;
    int bn = blockIdx.y * 64;
    int tid = threadIdx.x;
    int c = tid & 63, r = tid >> 6;
    for (int k = r; k < 64; k += 4)
        t[k][c] = w[(size_t)(bk + k) * FC1_OUT + bn + c];
    __syncthreads();
    for (int n = r; n < 64; n += 4)
        wt[(size_t)(bn + n) * FC1_IN + bk + c] = __float2bfloat16(t[c][n]);
}

// ---------------- FC1 MFMA: (832x2304 bf16)@(2304x1024 bf16^T)+b, relu -> f32 ---
__global__ __launch_bounds__(256) void fc1_mfma(const __hip_bfloat16* __restrict__ A,
                                                const __hip_bfloat16* __restrict__ WT,
                                                const float* __restrict__ bias,
                                                float* __restrict__ C) {
    __shared__ char smem[16384];   // As [64][128B] swz | Bs [64][128B] swz
    const int tid = threadIdx.x;
    const int w = tid >> 6, l = tid & 63;
    const int bm0 = blockIdx.x * 64, bn0 = blockIdx.y * 64;
    const char* Ab = (const char*)A;
    const char* Bb = (const char*)WT;

    f32x4 acc[2][2];
    #pragma unroll
    for (int i = 0; i < 2; ++i)
        #pragma unroll
        for (int j = 0; j < 2; ++j) acc[i][j] = (f32x4){0.f, 0.f, 0.f, 0.f};

    const int wr = (w >> 1) * 32, wc = (w & 1) * 32;
    const int lrow = l & 15;
    const int lkb  = (l >> 4) * 16;   // byte offset of this lane's 8-bf16 k-group

    for (int k0 = 0; k0 < FC1_IN; k0 += 64) {
        // stage 16 KiB: linear LDS dest, inverse-swizzled global source (rule 21)
        #pragma unroll
        for (int j = 0; j < 4; ++j) {
            int o = j * 4096 + tid * 16;
            const char* src;
            if (o < 8192) {
                int r = o >> 7, bby = o & 127;
                src = Ab + ((size_t)(bm0 + r) * FC1_IN + k0) * 2 + (bby ^ ((r & 7) << 4));
            } else {
                int o2 = o - 8192;
                int r = o2 >> 7, bby = o2 & 127;
                src = Bb + ((size_t)(bn0 + r) * FC1_IN + k0) * 2 + (bby ^ ((r & 7) << 4));
            }
            gload16(src, smem + o);
        }
        __syncthreads();   // drains vmcnt before use
        #pragma unroll
        for (int kk = 0; kk < 2; ++kk) {
            short8v af[2], bf[2];
            #pragma unroll
            for (int ms = 0; ms < 2; ++ms) {
                int r = wr + ms * 16 + lrow;
                int bby = kk * 64 + lkb;
                af[ms] = *(const short8v*)(smem + r * 128 + (bby ^ ((r & 7) << 4)));
            }
            #pragma unroll
            for (int ns = 0; ns < 2; ++ns) {
                int r = wc + ns * 16 + lrow;
                int bby = kk * 64 + lkb;
                bf[ns] = *(const short8v*)(smem + 8192 + r * 128 + (bby ^ ((r & 7) << 4)));
            }
            #pragma unroll
            for (int ms = 0; ms < 2; ++ms)
                #pragma unroll
                for (int ns = 0; ns < 2; ++ns)
                    acc[ms][ns] = __builtin_amdgcn_mfma_f32_16x16x32_bf16(
                        af[ms], bf[ns], acc[ms][ns], 0, 0, 0);
        }
        __syncthreads();
    }
    // epilogue: C/D layout col=lane&15, row=(lane>>4)*4+reg (m89-verified)
    const int col = l & 15, rbase = (l >> 4) * 4;
    #pragma unroll
    for (int ms = 0; ms < 2; ++ms)
        #pragma unroll
        for (int ns = 0; ns < 2; ++ns)
            #pragma unroll
            for (int j = 0; j < 4; ++j) {
                int gm = bm0 + wr + ms * 16 + rbase + j;
                int gn = bn0 + wc + ns * 16 + col;
                if (gm < NDET)
                    C[(size_t)gm * FC1_OUT + gn] = fmaxf(acc[ms][ns][j] + bias[gn], 0.0f);
            }
}

// ---------------- FC2: heads ----------------
__global__ __launch_bounds__(256) void fc2_kernel(const float* __restrict__ hdn,
                                                  const float* __restrict__ w_cls,
                                                  const float* __restrict__ b_cls,
                                                  const float* __restrict__ w_wh,
                                                  const float* __restrict__ b_wh,
                                                  float* __restrict__ out) {
    int n = blockIdx.x;
    int tid = threadIdx.x;
    int lane = tid & 63, wv = tid >> 6;
    const float* h = hdn + (size_t)n * FC1_OUT;
    for (int j = wv; j < 14; j += 4) {
        float s = 0.0f;
        if (j < 10) {
            for (int k2 = lane; k2 < FC1_OUT; k2 += 64) s += h[k2] * w_cls[k2 * 10 + j];
        } else {
            int jj = j - 10;
            for (int k2 = lane; k2 < FC1_OUT; k2 += 64) s += h[k2] * w_wh[k2 * 4 + jj];
        }
        #pragma unroll
        for (int off = 32; off > 0; off >>= 1) s += __shfl_down(s, off);
        if (lane == 0) {
            if (j < 10) out[O_CLS + n * 10 + j] = s + b_cls[j];
            else        out[O_SWH + n * 4 + (j - 10)] = s + b_wh[j - 10];
        }
    }
}

extern "C" void kernel_launch(void* const* d_in, const int* in_sizes, int n_in,
                              void* d_out, int out_size, void* d_ws, size_t ws_size,
                              hipStream_t stream) {
    const float* feat   = (const float*)d_in[0];
    const float* hm     = (const float*)d_in[1];
    const float* wh     = (const float*)d_in[2];
    const float* offset = (const float*)d_in[3];
    const float* w_fc1  = (const float*)d_in[4];
    const float* b_fc1  = (const float*)d_in[5];
    const float* w_cls  = (const float*)d_in[6];
    const float* b_cls  = (const float*)d_in[7];
    const float* w_wh   = (const float*)d_in[8];
    const float* b_wh   = (const float*)d_in[9];
    float* out = (float*)d_out;

    char* ws = (char*)d_ws;
    int*   ws_inds          = (int*)ws;                                  // 800 ints
    float* ws_boxes         = (float*)(ws + 4096);                       // 3200 f
    __hip_bfloat16* ws_wt   = (__hip_bfloat16*)(ws + 32768);             // 1024*2304 bf16
    __hip_bfloat16* ws_roi  = (__hip_bfloat16*)(ws + 32768 + 4718592);   // 832*2304 bf16
    float* ws_hdn           = (float*)(ws + 32768 + 4718592 + 3833856);  // 800*1024 f32

    // output 0: hm passthrough
    hipMemcpyAsync(out + O_HM, hm, (size_t)BS * NA * HW * sizeof(float),
                   hipMemcpyDeviceToDevice, stream);

    topk_kernel<<<BS, 1024, 0, stream>>>(hm, out, ws_inds);
    gather_kernel<<<(NDET + 255) / 256, 256, 0, stream>>>(wh, offset, ws_inds, out, ws_boxes);
    wt_kernel<<<dim3(FC1_IN / 64, FC1_OUT / 64), 256, 0, stream>>>(w_fc1, ws_wt);
    roi_kernel<<<MPAD, 256, 0, stream>>>(feat, ws_boxes, ws_roi);
    fc1_mfma<<<dim3(MPAD / 64, FC1_OUT / 64), 256, 0, stream>>>(ws_roi, ws_wt, b_fc1, ws_hdn);
    fc2_kernel<<<NDET, 256, 0, stream>>>(ws_hdn, w_cls, b_cls, w_wh, b_wh, out);
}

// Round 3
// 288.839 us; speedup vs baseline: 2.4418x; 1.0856x over previous
//
#include <hip/hip_runtime.h>
#include <hip/hip_bf16.h>
#include <stdint.h>

#define HW      16384
#define W_      128
#define NA      9
#define BS      8
#define K_TOP   100
#define NDET    800
#define MPAD    832
#define C_FEAT  256
#define FC1_IN  2304
#define FC1_OUT 1024

// output offsets (floats)
#define O_HM    0
#define O_WH1   1179648
#define O_OFF1  1182848
#define O_S1CLS 1184448
#define O_WH2   1185248
#define O_OFF2  1188448
#define O_CLS   1190048
#define O_SWH   1198048
#define O_INDS  1201248
#define O_VAL   1202048

#define NBIN     1024
#define CAND_MAX 512
#define HBLK     36            // blocks per batch for hist/collect (147456/36 = 4096 elems)

typedef __attribute__((ext_vector_type(8))) short short8v;
typedef __attribute__((ext_vector_type(4))) float f32x4;

__device__ __forceinline__ void gload16(const void* g, void* l) {
    __builtin_amdgcn_global_load_lds(
        (const __attribute__((address_space(1))) unsigned int*)g,
        (__attribute__((address_space(3))) unsigned int*)l, 16, 0, 0);
}

__device__ __forceinline__ int binof(float v) {
    return max(0, min(NBIN - 1, (int)(v * (float)NBIN)));
}

// ---- t1: per-batch histogram (LDS then global merge) + hm->out passthrough ----
__global__ __launch_bounds__(256) void hist_kernel(const float* __restrict__ hm,
                                                   float* __restrict__ out,
                                                   unsigned int* __restrict__ hist) {
    const int tid = threadIdx.x;
    const int b = blockIdx.x / HBLK, sub = blockIdx.x % HBLK;
    __shared__ unsigned int lh[NBIN];
    for (int i = tid; i < NBIN; i += 256) lh[i] = 0u;
    __syncthreads();
    const float4* src = (const float4*)(hm + (size_t)b * NA * HW) + sub * 1024;
    float4*       dst = (float4*)(out + O_HM + (size_t)b * NA * HW) + sub * 1024;
    #pragma unroll
    for (int t = 0; t < 4; ++t) {
        float4 v = src[t * 256 + tid];
        dst[t * 256 + tid] = v;
        atomicAdd(&lh[binof(v.x)], 1u);
        atomicAdd(&lh[binof(v.y)], 1u);
        atomicAdd(&lh[binof(v.z)], 1u);
        atomicAdd(&lh[binof(v.w)], 1u);
    }
    __syncthreads();
    for (int i = tid; i < NBIN; i += 256)
        if (lh[i]) atomicAdd(&hist[b * NBIN + i], lh[i]);
}

// ---- t2: threshold bin per batch (one wave per batch) ----
__global__ __launch_bounds__(512) void thresh_kernel(const unsigned int* __restrict__ hist,
                                                     int* __restrict__ thr) {
    const int b = threadIdx.x >> 6, lane = threadIdx.x & 63;
    const unsigned int* h = hist + b * NBIN;
    unsigned int s = 0;
    #pragma unroll
    for (int i = 0; i < 16; ++i) s += h[lane * 16 + i];
    // suffix sum across lanes: suf[l] = sum_{l'>=l} s[l']
    unsigned int suf = s;
    #pragma unroll
    for (int off = 1; off < 64; off <<= 1) {
        unsigned int o = __shfl_down(suf, off);
        if (lane + off < 64) suf += o;
    }
    unsigned long long mask = __ballot(suf >= K_TOP);
    int L = 63 - __clzll(mask);            // highest lane whose 16-bin range suffix >= K
    unsigned int below = __shfl(suf, L + 1);
    if (L == 63) below = 0;
    if (lane == L) {
        unsigned int acc = below;
        int T = 16 * L;
        for (int i = 15; i >= 0; --i) {
            acc += h[16 * L + i];
            if (acc >= K_TOP) { T = 16 * L + i; break; }
        }
        thr[b] = T;
    }
}

// ---- t3: collect candidates above threshold ----
__global__ __launch_bounds__(256) void collect_kernel(const float* __restrict__ hm,
                                                      const int* __restrict__ thr,
                                                      unsigned int* __restrict__ cnt,
                                                      unsigned long long* __restrict__ cand) {
    const int tid = threadIdx.x;
    const int b = blockIdx.x / HBLK, sub = blockIdx.x % HBLK;
    const int T = thr[b];
    const float4* src = (const float4*)(hm + (size_t)b * NA * HW) + sub * 1024;
    #pragma unroll
    for (int t = 0; t < 4; ++t) {
        int i4 = sub * 1024 + t * 256 + tid;
        float4 v4 = src[t * 256 + tid];
        float vv[4] = {v4.x, v4.y, v4.z, v4.w};
        #pragma unroll
        for (int e = 0; e < 4; ++e) {
            if (binof(vv[e]) >= T) {
                unsigned int p = atomicAdd(&cnt[b], 1u);
                if (p < CAND_MAX) {
                    int idx = i4 * 4 + e;
                    int a  = idx >> 14;
                    int pp = idx & (HW - 1);
                    unsigned int flat_i = (unsigned int)(pp * NA + a);
                    cand[b * CAND_MAX + p] =
                        ((unsigned long long)__float_as_uint(vv[e]) << 32)
                        | (unsigned long long)(0xFFFFFFFFu - flat_i);
                }
            }
        }
    }
}

// ---- t4: sort 512 candidates, emit top-100 outputs + gather wh/off + boxes ----
__global__ __launch_bounds__(512) void sort_kernel(const unsigned long long* __restrict__ cand,
                                                   const unsigned int* __restrict__ cntg,
                                                   const float* __restrict__ wh,
                                                   const float* __restrict__ offset,
                                                   float* __restrict__ out,
                                                   float* __restrict__ ws_boxes) {
    const int b = blockIdx.x, tid = threadIdx.x;
    __shared__ unsigned long long cd[CAND_MAX];
    unsigned int cnt = cntg[b]; if (cnt > CAND_MAX) cnt = CAND_MAX;
    cd[tid] = (tid < (int)cnt) ? cand[b * CAND_MAX + tid] : 0ull;
    __syncthreads();
    for (int k = 2; k <= CAND_MAX; k <<= 1) {
        for (int j = k >> 1; j > 0; j >>= 1) {
            int i = tid, ixj = i ^ j;
            if (ixj > i) {
                unsigned long long a = cd[i], bb = cd[ixj];
                bool up = ((i & k) == 0);
                if (up ? (a < bb) : (a > bb)) { cd[i] = bb; cd[ixj] = a; }
            }
            __syncthreads();
        }
    }
    if (tid < K_TOP) {
        unsigned long long key = cd[tid];
        float v = __uint_as_float((unsigned int)(key >> 32));
        unsigned int flat_i = 0xFFFFFFFFu - (unsigned int)(key & 0xFFFFFFFFull);
        int a = (int)(flat_i % NA);
        int p = (int)(flat_i / NA);
        int inds = p + b * HW;
        int o = b * K_TOP + tid;
        out[O_VAL + o]   = v;
        out[O_S1CLS + o] = (float)a;
        out[O_INDS + o]  = (float)inds;
        // gather (reference quirk: row index omits anchor term -> batch-0 slab,
        // p2 = inds/9, a2 = inds%9)
        int p2 = inds / NA;
        int a2 = inds - p2 * NA;
        float w0 = wh[(size_t)(a2 * 4 + 0) * HW + p2];
        float w1 = wh[(size_t)(a2 * 4 + 1) * HW + p2];
        float w2 = wh[(size_t)(a2 * 4 + 2) * HW + p2];
        float w3 = wh[(size_t)(a2 * 4 + 3) * HW + p2];
        float o0 = offset[(size_t)(a2 * 2 + 0) * HW + p2];
        float o1 = offset[(size_t)(a2 * 2 + 1) * HW + p2];
        out[O_WH1 + o * 4 + 0] = w0; out[O_WH1 + o * 4 + 1] = w1;
        out[O_WH1 + o * 4 + 2] = w2; out[O_WH1 + o * 4 + 3] = w3;
        out[O_WH2 + o * 4 + 0] = w0; out[O_WH2 + o * 4 + 1] = w1;
        out[O_WH2 + o * 4 + 2] = w2; out[O_WH2 + o * 4 + 3] = w3;
        out[O_OFF1 + o * 2 + 0] = o0; out[O_OFF1 + o * 2 + 1] = o1;
        out[O_OFF2 + o * 2 + 0] = o0; out[O_OFF2 + o * 2 + 1] = o1;
        float xs = (float)(inds % W_) + o0;   // == p % 128
        float ys = (float)(inds / W_) + o1;   // includes b*128 (reference quirk)
        ws_boxes[o * 4 + 0] = xs + w0;
        ws_boxes[o * 4 + 1] = ys + w1;
        ws_boxes[o * 4 + 2] = xs + w2;
        ws_boxes[o * 4 + 3] = ys + w3;
    }
}

// ---------------- roi align 3x3 -> bf16 A matrix [MPAD][2304] ----------------
__global__ __launch_bounds__(256) void roi_kernel(const float* __restrict__ feat,
                                                  const float* __restrict__ ws_boxes,
                                                  __hip_bfloat16* __restrict__ ws_roi) {
    int n = blockIdx.x;
    int c = threadIdx.x;
    __hip_bfloat16* op = ws_roi + (size_t)n * FC1_IN + (size_t)c * 9;
    if (n >= NDET) {   // zero-pad rows 800..831
        #pragma unroll
        for (int i = 0; i < 9; ++i) op[i] = __float2bfloat16(0.0f);
        return;
    }
    float x1 = ws_boxes[n * 4 + 0], y1 = ws_boxes[n * 4 + 1];
    float x2 = ws_boxes[n * 4 + 2], y2 = ws_boxes[n * 4 + 3];
    int b = n / K_TOP;
    float bw = fmaxf(x2 - x1, 1.0f) / 3.0f;
    float bh = fmaxf(y2 - y1, 1.0f) / 3.0f;
    const float* fb = feat + ((size_t)b * C_FEAT + c) * HW;
    #pragma unroll
    for (int gy = 0; gy < 3; ++gy) {
        float ysf = y1 + ((float)gy + 0.5f) * bh;
        #pragma unroll
        for (int gx = 0; gx < 3; ++gx) {
            float xsf = x1 + ((float)gx + 0.5f) * bw;
            bool invalid = (ysf < -1.0f) || (ysf > 128.0f) || (xsf < -1.0f) || (xsf > 128.0f);
            float y = fminf(fmaxf(ysf, 0.0f), 127.0f);
            float x = fminf(fmaxf(xsf, 0.0f), 127.0f);
            int y0 = (int)floorf(y);
            int x0 = (int)floorf(x);
            int y1i = min(y0 + 1, 127);
            int x1i = min(x0 + 1, 127);
            float ly = y - (float)y0, lx = x - (float)x0;
            float hy = 1.0f - ly, hx = 1.0f - lx;
            float v00 = fb[y0 * W_ + x0],  v01 = fb[y0 * W_ + x1i];
            float v10 = fb[y1i * W_ + x0], v11 = fb[y1i * W_ + x1i];
            float v = hy * hx * v00 + hy * lx * v01 + ly * hx * v10 + ly * lx * v11;
            op[gy * 3 + gx] = __float2bfloat16(invalid ? 0.0f : v);
        }
    }
}

// ---------------- W transpose+convert: [2304][1024] f32 -> [1024][2304] bf16 ----
__global__ __launch_bounds__(256) void wt_kernel(const float* __restrict__ w,
                                                 __hip_bfloat16* __restrict__ wt) {
    __shared__ float t[64][65];
    int bk = blockIdx.x * 64;
    int bn = blockIdx.y * 64;
    int tid = threadIdx.x;
    int c = tid & 63, r = tid >> 6;
    for (int k = r; k < 64; k += 4)
        t[k][c] = w[(size_t)(bk + k) * FC1_OUT + bn + c];
    __syncthreads();
    for (int n = r; n < 64; n += 4)
        wt[(size_t)(bn + n) * FC1_IN + bk + c] = __float2bfloat16(t[c][n]);
}

// ------- FC1 MFMA, 2-phase double-buffered: (832x2304)@(2304x1024^T)+b, relu ----
__global__ __launch_bounds__(256) void fc1_mfma(const __hip_bfloat16* __restrict__ A,
                                                const __hip_bfloat16* __restrict__ WT,
                                                const float* __restrict__ bias,
                                                float* __restrict__ C) {
    __shared__ char smem[32768];   // 2 x (As [64][128B] swz | Bs [64][128B] swz)
    const int tid = threadIdx.x;
    const int w = tid >> 6, l = tid & 63;
    const int bm0 = blockIdx.x * 64, bn0 = blockIdx.y * 64;
    const char* Ab = (const char*)A;
    const char* Bb = (const char*)WT;

    f32x4 acc[2][2];
    #pragma unroll
    for (int i = 0; i < 2; ++i)
        #pragma unroll
        for (int j = 0; j < 2; ++j) acc[i][j] = (f32x4){0.f, 0.f, 0.f, 0.f};

    const int wr = (w >> 1) * 32, wc = (w & 1) * 32;
    const int lrow = l & 15;
    const int lkb  = (l >> 4) * 16;

    auto STAGE = [&](int k0, int buf) {
        #pragma unroll
        for (int j = 0; j < 4; ++j) {
            int o = j * 4096 + tid * 16;
            const char* src;
            if (o < 8192) {
                int r = o >> 7, bby = o & 127;
                src = Ab + ((size_t)(bm0 + r) * FC1_IN + k0) * 2 + (bby ^ ((r & 7) << 4));
            } else {
                int o2 = o - 8192;
                int r = o2 >> 7, bby = o2 & 127;
                src = Bb + ((size_t)(bn0 + r) * FC1_IN + k0) * 2 + (bby ^ ((r & 7) << 4));
            }
            gload16(src, smem + buf * 16384 + o);
        }
    };

    STAGE(0, 0);
    __syncthreads();           // drains vmcnt(0)+lgkmcnt(0) before first compute
    int cur = 0;
    #pragma unroll 1
    for (int t = 0; t < FC1_IN / 64; ++t) {
        if (t + 1 < FC1_IN / 64) STAGE((t + 1) * 64, cur ^ 1);   // issue-early
        char* sb = smem + cur * 16384;
        #pragma unroll
        for (int kk = 0; kk < 2; ++kk) {
            short8v af[2], bf[2];
            #pragma unroll
            for (int ms = 0; ms < 2; ++ms) {
                int r = wr + ms * 16 + lrow;
                int bby = kk * 64 + lkb;
                af[ms] = *(const short8v*)(sb + r * 128 + (bby ^ ((r & 7) << 4)));
            }
            #pragma unroll
            for (int ns = 0; ns < 2; ++ns) {
                int r = wc + ns * 16 + lrow;
                int bby = kk * 64 + lkb;
                bf[ns] = *(const short8v*)(sb + 8192 + r * 128 + (bby ^ ((r & 7) << 4)));
            }
            #pragma unroll
            for (int ms = 0; ms < 2; ++ms)
                #pragma unroll
                for (int ns = 0; ns < 2; ++ns)
                    acc[ms][ns] = __builtin_amdgcn_mfma_f32_16x16x32_bf16(
                        af[ms], bf[ns], acc[ms][ns], 0, 0, 0);
        }
        __syncthreads();       // one barrier/iter: drains next-tile loads (overlapped)
        cur ^= 1;
    }
    const int col = l & 15, rbase = (l >> 4) * 4;
    #pragma unroll
    for (int ms = 0; ms < 2; ++ms)
        #pragma unroll
        for (int ns = 0; ns < 2; ++ns)
            #pragma unroll
            for (int j = 0; j < 4; ++j) {
                int gm = bm0 + wr + ms * 16 + rbase + j;
                int gn = bn0 + wc + ns * 16 + col;
                if (gm < NDET)
                    C[(size_t)gm * FC1_OUT + gn] = fmaxf(acc[ms][ns][j] + bias[gn], 0.0f);
            }
}

// ---- FC2 prep: pack heads transposed -> wT14[14][1024] f32 ----
__global__ __launch_bounds__(256) void fc2prep_kernel(const float* __restrict__ w_cls,
                                                      const float* __restrict__ w_wh,
                                                      float* __restrict__ wT14) {
    int idx = blockIdx.x * 256 + threadIdx.x;   // 56 blocks x 256 = 14336
    int j = idx >> 10, k = idx & 1023;
    wT14[idx] = (j < 10) ? w_cls[k * 10 + j] : w_wh[k * 4 + (j - 10)];
}

// ---- FC2: heads, coalesced float4 dots ----
__global__ __launch_bounds__(256) void fc2_kernel(const float* __restrict__ hdn,
                                                  const float* __restrict__ wT14,
                                                  const float* __restrict__ b_cls,
                                                  const float* __restrict__ b_wh,
                                                  float* __restrict__ out) {
    int n = blockIdx.x;
    int lane = threadIdx.x & 63, wv = threadIdx.x >> 6;
    const float4* h4 = (const float4*)(hdn + (size_t)n * FC1_OUT);
    for (int j = wv; j < 14; j += 4) {
        const float4* w4 = (const float4*)(wT14 + (size_t)j * FC1_OUT);
        float s = 0.0f;
        #pragma unroll
        for (int t = 0; t < 4; ++t) {
            float4 a = h4[t * 64 + lane], b = w4[t * 64 + lane];
            s += a.x * b.x + a.y * b.y + a.z * b.z + a.w * b.w;
        }
        #pragma unroll
        for (int off = 32; off > 0; off >>= 1) s += __shfl_down(s, off);
        if (lane == 0) {
            if (j < 10) out[O_CLS + n * 10 + j] = s + b_cls[j];
            else        out[O_SWH + n * 4 + (j - 10)] = s + b_wh[j - 10];
        }
    }
}

extern "C" void kernel_launch(void* const* d_in, const int* in_sizes, int n_in,
                              void* d_out, int out_size, void* d_ws, size_t ws_size,
                              hipStream_t stream) {
    const float* feat   = (const float*)d_in[0];
    const float* hm     = (const float*)d_in[1];
    const float* wh     = (const float*)d_in[2];
    const float* offset = (const float*)d_in[3];
    const float* w_fc1  = (const float*)d_in[4];
    const float* b_fc1  = (const float*)d_in[5];
    const float* w_cls  = (const float*)d_in[6];
    const float* b_cls  = (const float*)d_in[7];
    const float* w_wh   = (const float*)d_in[8];
    const float* b_wh   = (const float*)d_in[9];
    float* out = (float*)d_out;

    char* ws = (char*)d_ws;
    float*              ws_boxes = (float*)(ws + 4096);                 // 3200 f
    unsigned int*       ws_hist  = (unsigned int*)(ws + 20480);         // 8x1024 u32
    unsigned int*       ws_cnt   = (unsigned int*)(ws + 53248);         // 8 u32
    int*                ws_thr   = (int*)(ws + 53280);                  // 8 i32
    unsigned long long* ws_cand  = (unsigned long long*)(ws + 57344);   // 8x512 u64
    __hip_bfloat16*     ws_wt    = (__hip_bfloat16*)(ws + 98304);       // 1024x2304
    __hip_bfloat16*     ws_roi   = (__hip_bfloat16*)(ws + 98304 + 4718592);
    float*              ws_hdn   = (float*)(ws + 98304 + 4718592 + 3833856);
    float*              ws_wT14  = (float*)(ws + 98304 + 4718592 + 3833856 + 3276800);

    hipMemsetAsync(ws + 20480, 0, 32832, stream);   // hist + cnt (+thr)

    hist_kernel   <<<BS * HBLK, 256, 0, stream>>>(hm, out, ws_hist);
    thresh_kernel <<<1, 512, 0, stream>>>(ws_hist, ws_thr);
    collect_kernel<<<BS * HBLK, 256, 0, stream>>>(hm, ws_thr, ws_cnt, ws_cand);
    sort_kernel   <<<BS, 512, 0, stream>>>(ws_cand, ws_cnt, wh, offset, out, ws_boxes);
    wt_kernel     <<<dim3(FC1_IN / 64, FC1_OUT / 64), 256, 0, stream>>>(w_fc1, ws_wt);
    roi_kernel    <<<MPAD, 256, 0, stream>>>(feat, ws_boxes, ws_roi);
    fc1_mfma      <<<dim3(MPAD / 64, FC1_OUT / 64), 256, 0, stream>>>(ws_roi, ws_wt, b_fc1, ws_hdn);
    fc2prep_kernel<<<56, 256, 0, stream>>>(w_cls, w_wh, ws_wT14);
    fc2_kernel    <<<NDET, 256, 0, stream>>>(ws_hdn, ws_wT14, b_cls, b_wh, out);
}